// Round 10
// baseline (164.051 us; speedup 1.0000x reference)
//
#include <hip/hip_runtime.h>
#include <math.h>

#define CCH 512
#define SSQ 2048           // M*T
#define MTOT 4096          // B*S rows

typedef __bf16 bf16;
typedef __bf16 bf16x8 __attribute__((ext_vector_type(8)));
typedef __bf16 bf16x4 __attribute__((ext_vector_type(4)));
typedef float  f32x4  __attribute__((ext_vector_type(4)));

#define AS1 __attribute__((address_space(1)))
#define AS3 __attribute__((address_space(3)))
__device__ __forceinline__ void glds16(const void* g, void* l) {
    __builtin_amdgcn_global_load_lds((const AS1 void*)g, (AS3 void*)l, 16, 0, 0);
}
// raw v_exp_f32: computes 2^x (masked lanes: 2^-10000 flushes to 0)
__device__ __forceinline__ float fexp2(float x) {
    float r; asm("v_exp_f32 %0, %1" : "=v"(r) : "v"(x)); return r;
}

// ---------------- fused prep: GN-stats (0..255) + weight transpose (256..575)
// + combined bias bc = attn_b@out_w + out_b (576..577) + bf16 copy of attn_w (578..641)
__global__ __launch_bounds__(256) void gnw_kernel(const float* __restrict__ x,
        float* __restrict__ mu, float* __restrict__ rstd,
        const float* __restrict__ w0, const float* __restrict__ w1,
        const float* __restrict__ w2, const float* __restrict__ w3,
        const float* __restrict__ w4, bf16* __restrict__ wT,
        const float* __restrict__ attnb, const float* __restrict__ outb,
        float* __restrict__ bcv) {
    __shared__ float smem[64*65];
    int tid = threadIdx.x;
    if (blockIdx.x < 256) {
        float* s_sum = smem;
        float* s_sq  = smem + 256;
        int bg = blockIdx.x;
        long base = (long)bg * 8192;
        float sum = 0.f, sq = 0.f;
#pragma unroll
        for (int r = 0; r < 32; ++r) {
            float v = x[base + r*256 + tid];
            sum += v; sq += v*v;
        }
        s_sum[tid] = sum; s_sq[tid] = sq;
        __syncthreads();
        for (int off = 128; off > 0; off >>= 1) {
            if (tid < off) { s_sum[tid] += s_sum[tid+off]; s_sq[tid] += s_sq[tid+off]; }
            __syncthreads();
        }
        if (tid == 0) {
            float m = s_sum[0] * (1.f/8192.f);
            float v = s_sq[0]  * (1.f/8192.f) - m*m;
            mu[bg] = m;
            rstd[bg] = rsqrtf(v + 1e-5f);
        }
    } else if (blockIdx.x < 576) {
        int bid = blockIdx.x - 256;
        int z = bid >> 6, r2 = bid & 63;
        int k0 = (r2 >> 3)*64, n0 = (r2 & 7)*64;
        const float* srcs[5] = {w0, w1, w2, w3, w4};
        const float* W = srcs[z];
        bf16* D = wT + (long)z * (CCH*CCH);
        float (*t)[65] = (float(*)[65])smem;
        int cI = tid & 63, r4 = tid >> 6;
#pragma unroll
        for (int p = 0; p < 16; ++p) {
            int kr = p*4 + r4;
            t[kr][cI] = W[(long)(k0+kr)*CCH + n0 + cI];
        }
        __syncthreads();
#pragma unroll
        for (int p = 0; p < 16; ++p) {
            int nr = p*4 + r4;
            D[(long)(n0+nr)*CCH + k0 + cI] = (bf16)t[cI][nr];
        }
    } else if (blockIdx.x < 578) {
        // bc[n] = out_b[n] + sum_j attn_b[j] * out_w[j][n]
        int n = (blockIdx.x - 576)*256 + tid;
        float a = outb[n];
#pragma unroll 16
        for (int j = 0; j < 512; ++j)
            a = fmaf(attnb[j], w4[(long)j*CCH + n], a);
        bcv[n] = a;
    } else {
        // straight bf16 copy of attn_w into wT slot 5
        bf16* wAc = wT + (long)5*CCH*CCH;
        int base = (blockIdx.x - 578)*4096 + tid;
#pragma unroll
        for (int p = 0; p < 16; ++p)
            wAc[base + p*256] = (bf16)w3[base + p*256];
    }
}

// ---------------- transpose+norm: x (B,C,S) fp32 -> xnT (B,S,C) bf16
__global__ void tn_kernel(const float* __restrict__ x, const float* __restrict__ mu,
                          const float* __restrict__ rstd, const float* __restrict__ gsc,
                          const float* __restrict__ gbs, bf16* __restrict__ xnT) {
    __shared__ float t[64][65];
    int s0 = blockIdx.x*64, c0 = blockIdx.y*64, b = blockIdx.z;
    int tid = threadIdx.x;
    int cI = tid & 63, r4 = tid >> 6;
#pragma unroll
    for (int p = 0; p < 16; ++p) {
        int cr = p*4 + r4;
        t[cr][cI] = x[((long)(b*CCH + c0 + cr))*SSQ + s0 + cI];
    }
    __syncthreads();
#pragma unroll
    for (int p = 0; p < 16; ++p) {
        int sr = p*4 + r4;
        int c = c0 + cI;
        int g = b*128 + (c >> 2);
        float v = (t[cI][sr] - mu[g]) * rstd[g] * gsc[c] + gbs[c];
        xnT[((long)(b*SSQ + s0 + sr))*CCH + c] = (bf16)v;
    }
}

// ---------------- fused depthwise 3x3 (SAME) q/k/v on (B,S,C) bf16
__global__ __launch_bounds__(256) void dw3_kernel(const bf16* __restrict__ xnT,
        const float* __restrict__ dwq, const float* __restrict__ dwk,
        const float* __restrict__ dwv,
        bf16* __restrict__ yq, bf16* __restrict__ yk, bf16* __restrict__ yv) {
    int tid = threadIdx.x;
    int cc = (tid & 63) * 8;
    int s  = blockIdx.x*4 + (tid >> 6);
    int sl = s & (SSQ-1);
    int b  = s >> 11;
    int m = sl >> 7, t = sl & 127;
    float aq[8] = {}, ak[8] = {}, av[8] = {};
#pragma unroll
    for (int di = 0; di < 3; ++di) {
        int m2 = m + di - 1;
        if ((unsigned)m2 >= 16u) continue;
#pragma unroll
        for (int dj = 0; dj < 3; ++dj) {
            int t2 = t + dj - 1;
            if ((unsigned)t2 >= 128u) continue;
            bf16x8 xv = *(const bf16x8*)(xnT + ((long)(b*SSQ + m2*128 + t2))*CCH + cc);
            int wi = (di*3 + dj)*CCH + cc;
#pragma unroll
            for (int i = 0; i < 8; ++i) {
                float xf = (float)xv[i];
                aq[i] += xf * dwq[wi+i];
                ak[i] += xf * dwk[wi+i];
                av[i] += xf * dwv[wi+i];
            }
        }
    }
    bf16x8 oq, ok, ov;
#pragma unroll
    for (int i = 0; i < 8; ++i) { oq[i] = (bf16)aq[i]; ok[i] = (bf16)ak[i]; ov[i] = (bf16)av[i]; }
    long o = (long)s*CCH + cc;
    *(bf16x8*)(yq + o) = oq;
    *(bf16x8*)(yk + o) = ok;
    *(bf16x8*)(yv + o) = ov;
}

// ---------------- GEMM core, m97 structure: BM=128, BN=NFR*32, BK=64.
template<int NFR>
__device__ __forceinline__ void gemm_core128(const bf16* __restrict__ A,
        const bf16* __restrict__ Wt, int m0, int n0,
        bf16* As, bf16* Bs, f32x4 (&acc)[4][NFR]) {
    int tid = threadIdx.x, lane = tid & 63, wid = tid >> 6;
    int sw = wid & 1, nw = wid >> 1;
    int col = lane & 15, quad = lane >> 4;
    const char* gA[4]; char* ldsA[4];
#pragma unroll
    for (int p = 0; p < 4; ++p) {
        int ci = tid + p*256;              // 1024 chunks of 16B (128 rows x 8)
        int row = ci >> 3;
        int c = (ci & 7) ^ (row & 7);
        gA[p] = (const char*)A + ((long)(m0+row)*CCH + c*8)*2;
        ldsA[p] = (char*)As + ci*16;
    }
    const char* gB[NFR]; char* ldsB[NFR];
#pragma unroll
    for (int p = 0; p < NFR; ++p) {
        int ci = tid + p*256;              // NFR*256 chunks (BN rows x 8)
        int row = ci >> 3;
        int c = (ci & 7) ^ (row & 7);
        gB[p] = (const char*)Wt + ((long)(n0+row)*CCH + c*8)*2;
        ldsB[p] = (char*)Bs + ci*16;
    }
    int rowA = sw*64 + col;
    int rowB = nw*(NFR*16) + col;
    for (int k0 = 0; k0 < CCH; k0 += 64) {
        __syncthreads();
#pragma unroll
        for (int p = 0; p < 4; ++p)   glds16(gA[p] + k0*2, ldsA[p]);
#pragma unroll
        for (int p = 0; p < NFR; ++p) glds16(gB[p] + k0*2, ldsB[p]);
        __syncthreads();
        bf16x8 af[4][2], bfr[NFR][2];
#pragma unroll
        for (int mt = 0; mt < 4; ++mt) {
            int r = rowA + mt*16;
#pragma unroll
            for (int ks = 0; ks < 2; ++ks) {
                int c = (ks*4 + quad) ^ (r & 7);
                af[mt][ks] = *(const bf16x8*)((char*)As + r*128 + c*16);
            }
        }
#pragma unroll
        for (int nt = 0; nt < NFR; ++nt) {
            int r = rowB + nt*16;
#pragma unroll
            for (int ks = 0; ks < 2; ++ks) {
                int c = (ks*4 + quad) ^ (r & 7);
                bfr[nt][ks] = *(const bf16x8*)((char*)Bs + r*128 + c*16);
            }
        }
#pragma unroll
        for (int ks = 0; ks < 2; ++ks)
#pragma unroll
            for (int mt = 0; mt < 4; ++mt)
#pragma unroll
                for (int nt = 0; nt < NFR; ++nt)
                    acc[mt][nt] = __builtin_amdgcn_mfma_f32_16x16x32_bf16(
                        af[mt][ks], bfr[nt][ks], acc[mt][nt], 0,0,0);
    }
}

// ---------------- fused QKV GEMM, 128x128 tiles (NFR=4)
// z=0: rope*(0.125*log2e) -> qout (attn uses exp2); z=1: rope -> kout
// z=2: transpose -> vout (B,C,S) with key order PERMUTED within each 32-key
//      block (pos = quad*8 + sub16*4 + r) so attn's PV B-frag is one b128
// z=3 (blocks x<4): WcT = (Wa@Wo)^T from wTo,wAc -> wT slot 6
__global__ __launch_bounds__(256) void gemm_qkv(const bf16* __restrict__ Abase,
        bf16* __restrict__ wT, bf16* __restrict__ qout,
        bf16* __restrict__ kout, bf16* __restrict__ vout) {
    __shared__ bf16 As[128*64];
    __shared__ bf16 Bs[128*64];
    int z = blockIdx.z;
    if (z == 3 && blockIdx.x >= 4) return;
    int m0 = blockIdx.x*128, n0 = blockIdx.y*128;
    const bf16* Aop = (z < 3) ? Abase + (long)z*MTOT*CCH : wT + (long)4*CCH*CCH;
    const bf16* Wop = (z < 3) ? wT + (long)z*CCH*CCH   : wT + (long)5*CCH*CCH;
    f32x4 acc[4][4] = {};
    gemm_core128<4>(Aop, Wop, m0, n0, As, Bs, acc);
    int tid = threadIdx.x, lane = tid & 63, wid = tid >> 6;
    int sw = wid & 1, nw = wid >> 1;
    int col = lane & 15, quad = lane >> 4;
    int nbase = n0 + nw*64;            // one full head (64 ch), head-aligned
    int mb = m0 + sw*64;
    if (z == 3) {
        bf16* wCt = wT + (long)6*CCH*CCH;
#pragma unroll
        for (int nt = 0; nt < 4; ++nt) {
            int n = nbase + nt*16 + col;
#pragma unroll
            for (int mt = 0; mt < 4; ++mt)
#pragma unroll
                for (int r = 0; r < 4; ++r)
                    wCt[(long)(mb + mt*16 + quad*4 + r)*CCH + n] = (bf16)acc[mt][nt][r];
        }
    } else if (z < 2) {
        bf16* outp = z ? kout : qout;
        const float sc = z ? 1.0f : 0.18033688f;   // 0.125 * log2(e)
        float invf = __expf(-(float)col * 0.5756462732485114f);  // 10000^(-col/16)
#pragma unroll
        for (int mt = 0; mt < 4; ++mt)
#pragma unroll
            for (int r = 0; r < 4; ++r) {
                int row = mb + mt*16 + quad*4 + r;
                int sl = row & (SSQ-1);
#pragma unroll
                for (int half = 0; half < 2; ++half) {   // 0: f-rot (pos=m), 1: t-rot (pos=t)
                    float pos = half ? (float)(sl & 127) : (float)(sl >> 7);
                    float ang = pos * invf;
                    float sn, cs;
                    __sincosf(ang, &sn, &cs);
                    float x1 = acc[mt][half*2+0][r], x2 = acc[mt][half*2+1][r];
                    outp[(long)row*CCH + nbase + half*32 + col]      = (bf16)((x1*cs - x2*sn)*sc);
                    outp[(long)row*CCH + nbase + half*32 + 16 + col] = (bf16)((x1*sn + x2*cs)*sc);
                }
            }
    } else {
#pragma unroll
        for (int mt = 0; mt < 4; ++mt)
#pragma unroll
            for (int nt = 0; nt < 4; ++nt) {
                int n = nbase + nt*16 + col;
                int row0 = mb + mt*16 + quad*4;
                int bq = row0 >> 11, sl0 = row0 & (SSQ-1);
                int sub16 = (sl0 >> 4) & 1;
                long slp = (long)(sl0 & ~31) + quad*8 + sub16*4;
                bf16x4 pk;
#pragma unroll
                for (int r = 0; r < 4; ++r) pk[r] = (bf16)acc[mt][nt][r];
                *(bf16x4*)(vout + ((long)(bq*CCH + n))*SSQ + slp) = pk;
            }
    }
}

// ---------------- projection GEMM (128x64): +bias+resid -> fp32 (B,C,S) [d_out]
__global__ __launch_bounds__(256) void gemm_out(const bf16* __restrict__ A,
        const bf16* __restrict__ Wt, const float* __restrict__ bias,
        const float* __restrict__ resid, float* __restrict__ outp) {
    __shared__ bf16 As[128*64];
    __shared__ bf16 Bs[64*64];
    int m0 = blockIdx.x*128, n0 = blockIdx.y*64;
    f32x4 acc[4][2] = {};
    gemm_core128<2>(A, Wt, m0, n0, As, Bs, acc);
    int tid = threadIdx.x, lane = tid & 63, wid = tid >> 6;
    int sw = wid & 1, nw = wid >> 1;
    int col = lane & 15, quad = lane >> 4;
    int nb = n0 + nw*32, mb = m0 + sw*64;
#pragma unroll
    for (int mt = 0; mt < 4; ++mt)
#pragma unroll
        for (int nt = 0; nt < 2; ++nt) {
            int n = nb + nt*16 + col;
            float bv = bias[n];
            int row0 = mb + mt*16 + quad*4;
            int b = row0 >> 11, sl0 = row0 & (SSQ-1);
            long off = ((long)(b*CCH + n))*SSQ + sl0;
            float4 rr = *(const float4*)(resid + off);
            float4 o4;
            o4.x = acc[mt][nt][0] + bv + rr.x;
            o4.y = acc[mt][nt][1] + bv + rr.y;
            o4.z = acc[mt][nt][2] + bv + rr.z;
            o4.w = acc[mt][nt][3] + bv + rr.w;
            *(float4*)(outp + off) = o4;
        }
}

// ---------------- MFMA flash attention v12: V DIRECT-TO-REGISTER.
// Wave = 32-key slice x 64 q-rows (R6 structure). K: glds16 -> LDS dbuf
// (2x16KB), counted vmcnt (never 0 in-loop). V: plain global->register loads,
// double reg buffers (vA/vB), 1-tile-ahead prefetch — no V LDS round trip,
// no V ds_reads (each V cell read by exactly one lane; pre-permuted layout).
// exp2 path: q pre-scaled by 0.125*log2e, raw v_exp_f32. 2-pass epilogue merge
// through the 32KB K-LDS overlay.
__device__ __forceinline__ void attn_tile12(int t, const char* ldsKr, char* ldsK,
        const char* const (&gK)[4], const char* const (&gV)[4],
        const bf16x8 (&qf)[4][2], int thr, int col, int quad, int kc0, int kc1,
        bf16x8 (&vCur)[4], bf16x8 (&vNxt)[4], f32x4 (&of)[4][4], float (&ls)[4]) {
    if (t == 15) { asm volatile("s_waitcnt vmcnt(4)" ::: "memory"); }
    else         { asm volatile("s_waitcnt vmcnt(8)" ::: "memory"); }
    __builtin_amdgcn_sched_barrier(0);
    const char* K = ldsKr + (t & 1)*16384;
    bf16x8 kf[2][2];
#pragma unroll
    for (int sub = 0; sub < 2; ++sub) {
        kf[sub][0] = *(const bf16x8*)(K + sub*2048 + col*128 + kc0);
        kf[sub][1] = *(const bf16x8*)(K + sub*2048 + col*128 + kc1);
    }
    asm volatile("s_waitcnt lgkmcnt(0)" ::: "memory");
    __builtin_amdgcn_sched_barrier(0);
    // stage K(t+2) into the region just freed; prefetch V(t+1) into vNxt
    if (t < 14) {
#pragma unroll
        for (int j = 0; j < 4; ++j)
            glds16(gK[j] + (long)(t+2)*131072, ldsK + (t & 1)*16384 + j*1024);
    }
    if (t < 15) {
#pragma unroll
        for (int j = 0; j < 4; ++j)
            vNxt[j] = *(const bf16x8*)(gV[j] + (long)(t+1)*256);
    }
    __builtin_amdgcn_sched_barrier(0);
    // ---- S^T = K Q^T on this wave's 32-key slice, mask via C-init
    f32x4 sc[2][4];
#pragma unroll
    for (int sub = 0; sub < 2; ++sub) {
        f32x4 m;
#pragma unroll
        for (int r = 0; r < 4; ++r) m[r] = (sub*16 + r < thr) ? 0.f : -10000.f;
#pragma unroll
        for (int qt = 0; qt < 4; ++qt) sc[sub][qt] = m;
    }
    __builtin_amdgcn_s_setprio(1);
#pragma unroll
    for (int sub = 0; sub < 2; ++sub)
#pragma unroll
        for (int qt = 0; qt < 4; ++qt) {
            sc[sub][qt] = __builtin_amdgcn_mfma_f32_16x16x32_bf16(kf[sub][0], qf[qt][0], sc[sub][qt], 0,0,0);
            sc[sub][qt] = __builtin_amdgcn_mfma_f32_16x16x32_bf16(kf[sub][1], qf[qt][1], sc[sub][qt], 0,0,0);
        }
    __builtin_amdgcn_s_setprio(0);
    // ---- exp2 -> register P fragments (k-slot order matches permuted V)
    bf16x8 pf[4];
#pragma unroll
    for (int qt = 0; qt < 4; ++qt) {
        float s = 0.f;
#pragma unroll
        for (int r = 0; r < 4; ++r) {
            float e0 = fexp2(sc[0][qt][r]);
            float e1 = fexp2(sc[1][qt][r]);
            pf[qt][r]     = (bf16)e0;
            pf[qt][4 + r] = (bf16)e1;
            s += e0 + e1;
        }
        ls[qt] += s;
    }
    // ---- O += P V (register V, reused by 4 q-subtiles)
    __builtin_amdgcn_s_setprio(1);
#pragma unroll
    for (int dt = 0; dt < 4; ++dt)
#pragma unroll
        for (int qt = 0; qt < 4; ++qt)
            of[qt][dt] = __builtin_amdgcn_mfma_f32_16x16x32_bf16(pf[qt], vCur[dt], of[qt][dt], 0,0,0);
    __builtin_amdgcn_s_setprio(0);
}

__global__ __launch_bounds__(256, 2) void attn_kernel(
        const bf16* __restrict__ qb, const bf16* __restrict__ kb,
        const bf16* __restrict__ vb, const int* __restrict__ lengths,
        bf16* __restrict__ o) {
    __shared__ char Ks[2][16384];        // K dbuf only (32KB); epilogue overlay
    __shared__ float Lsm[4][4][16];      // [wave][qt][col]
    int bid = blockIdx.x;
    int bh = bid & 15, qtb = bid >> 4;   // bh low bits -> XCD locality for K/V
    int b = bh >> 3, h = bh & 7;
    int tid = threadIdx.x, wid = tid >> 6, lane = tid & 63;
    int col = lane & 15, quad = lane >> 4;
    int q0 = qtb*64;
    int lenb = lengths[b];
    int thr = lenb - wid*32 - quad*4;    // key sub*16+r valid iff sub*16+r < thr

    const char* gK[4]; const char* gV[4];
#pragma unroll
    for (int j = 0; j < 4; ++j) {
        int s = j*64 + lane;
        int rl = s >> 3;
        int cin = s & 7;
        int csrc = cin ^ (rl & 7);
        gK[j] = (const char*)kb + ((long)(b*SSQ + wid*32 + rl))*1024 + h*128 + csrc*16;
        gV[j] = (const char*)vb + ((long)(b*CCH + h*64 + j*16 + col))*4096 + (wid*4 + quad)*16;
    }
    char* ldsK = (char*)Ks + wid*4096 + lane*16;   // write base (+buf*16384+j*1024)
    const char* ldsKr = (const char*)Ks + wid*4096; // read base (+buf*16384)

    const bf16* qp = qb + (long)(b*SSQ)*CCH + h*64;
    bf16x8 qf[4][2];
#pragma unroll
    for (int qt = 0; qt < 4; ++qt)
#pragma unroll
        for (int dc = 0; dc < 2; ++dc)
            qf[qt][dc] = *(const bf16x8*)(qp + (long)(q0 + qt*16 + col)*CCH + dc*32 + quad*8);

    f32x4 of[4][4] = {};
    float ls[4] = {};
    int cswz7 = col & 7;
    int kc0 = (quad ^ cswz7)*16;              // dc=0 chunk
    int kc1 = ((4 + quad) ^ cswz7)*16;        // dc=1 chunk

    // prologue: stage K(0), K(1); load V(0) -> vA.  (12 VMEM outstanding)
    bf16x8 vA[4], vB[4];
#pragma unroll
    for (int j = 0; j < 4; ++j) glds16(gK[j], ldsK + j*1024);
#pragma unroll
    for (int j = 0; j < 4; ++j) glds16(gK[j] + 131072L, ldsK + 16384 + j*1024);
#pragma unroll
    for (int j = 0; j < 4; ++j) vA[j] = *(const bf16x8*)(gV[j]);

    for (int t2 = 0; t2 < 16; t2 += 2) {
        attn_tile12(t2,     ldsKr, ldsK, gK, gV, qf, thr, col, quad, kc0, kc1, vA, vB, of, ls);
        attn_tile12(t2 + 1, ldsKr, ldsK, gK, gV, qf, thr, col, quad, kc0, kc1, vB, vA, of, ls);
    }

    // lsum: reduce over quads -> lane col holds this wave's slice-sum for row qt*16+col
#pragma unroll
    for (int qt = 0; qt < 4; ++qt) {
        ls[qt] += __shfl_xor(ls[qt], 16);
        ls[qt] += __shfl_xor(ls[qt], 32);
    }
    __syncthreads();                     // all waves done with K LDS -> overlay safe
    // 2-pass cross-wave merge through 32KB overlay: Om = [wave][64 rows][32 d]
    float* Om = (float*)Ks;
    bf16* ob = o + (long)(b*SSQ + q0)*CCH + h*64;
    int dl = lane & 31, rh = lane >> 5;
#pragma unroll
    for (int p = 0; p < 2; ++p) {
        if (p) __syncthreads();
#pragma unroll
        for (int qt = 0; qt < 4; ++qt)
#pragma unroll
            for (int dtl = 0; dtl < 2; ++dtl)
#pragma unroll
                for (int r = 0; r < 4; ++r)
                    Om[(wid*64 + qt*16 + quad*4 + r)*32 + dtl*16 + col] = of[qt][p*2 + dtl][r];
        if (p == 0 && quad == 0)
#pragma unroll
            for (int qt = 0; qt < 4; ++qt) Lsm[wid][qt][col] = ls[qt];
        __syncthreads();
        // wave w finalizes rows [w*16, w*16+16), d = p*32 + dl (2 rows per iter)
#pragma unroll
        for (int it = 0; it < 8; ++it) {
            int rr = wid*16 + it*2 + rh;
            float v = Om[rr*32 + dl] + Om[(64 + rr)*32 + dl]
                    + Om[(128 + rr)*32 + dl] + Om[(192 + rr)*32 + dl];
            float l = Lsm[0][rr>>4][rr&15] + Lsm[1][rr>>4][rr&15]
                    + Lsm[2][rr>>4][rr&15] + Lsm[3][rr>>4][rr&15];
            ob[(long)rr*CCH + p*32 + dl] = (bf16)(v / l);
        }
    }
}

extern "C" void kernel_launch(void* const* d_in, const int* in_sizes, int n_in,
                              void* d_out, int out_size, void* d_ws, size_t ws_size,
                              hipStream_t stream) {
    const float* x        = (const float*)d_in[0];
    const int*   lengths  = (const int*)  d_in[1];
    const float* gn_scale = (const float*)d_in[2];
    const float* gn_bias  = (const float*)d_in[3];
    const float* dw_q     = (const float*)d_in[4];
    const float* dw_k     = (const float*)d_in[5];
    const float* dw_v     = (const float*)d_in[6];
    const float* pw_q     = (const float*)d_in[7];
    const float* pw_k     = (const float*)d_in[8];
    const float* pw_v     = (const float*)d_in[9];
    const float* attn_w   = (const float*)d_in[10];
    const float* attn_b   = (const float*)d_in[11];
    const float* out_w    = (const float*)d_in[12];
    const float* out_b    = (const float*)d_in[13];
    float* out = (float*)d_out;

    char* w = (char*)d_ws;
    float* mu   = (float*)w;
    float* rstd = (float*)(w + 1024);
    float* bcv  = (float*)(w + 2048);
    bf16* wT    = (bf16*)(w + 4096);          // 7 slots x 512KB:
                                              // 0..2 pw_{q,k,v}^T, 3 Wa^T, 4 Wo^T, 5 Wa, 6 Wc^T
    bf16* wCt = wT + (long)6*CCH*CCH;
    bf16* xnT  = (bf16*)(w + 0x00400000);
    bf16* yT   = (bf16*)(w + 0x00800000);     // yq|yk|yv contiguous, 4MB each
    bf16* qbf  = (bf16*)(w + 0x01400000);
    bf16* kbf  = (bf16*)(w + 0x01800000);
    bf16* vbf  = (bf16*)(w + 0x01C00000);
    bf16* obf  = (bf16*)(w + 0x02000000);

    gnw_kernel<<<642, 256, 0, stream>>>(x, mu, rstd, pw_q, pw_k, pw_v, attn_w, out_w,
                                        wT, attn_b, out_b, bcv);
    tn_kernel<<<dim3(32,8,2), 256, 0, stream>>>(x, mu, rstd, gn_scale, gn_bias, xnT);
    dw3_kernel<<<MTOT/4, 256, 0, stream>>>(xnT, dw_q, dw_k, dw_v,
                                           yT, yT + (long)MTOT*CCH, yT + (long)2*MTOT*CCH);

    gemm_qkv<<<dim3(MTOT/128, CCH/128, 4), 256, 0, stream>>>(yT, wT, qbf, kbf, vbf);

    attn_kernel<<<512, 256, 0, stream>>>(qbf, kbf, vbf, lengths, obf);

    gemm_out<<<dim3(MTOT/128, CCH/64), 256, 0, stream>>>(obf, wCt, bcv, x, out);
}

// Round 11
// 155.102 us; speedup vs baseline: 1.0577x; 1.0577x over previous
//
#include <hip/hip_runtime.h>
#include <math.h>

#define CCH 512
#define SSQ 2048           // M*T
#define MTOT 4096          // B*S rows

typedef __bf16 bf16;
typedef __bf16 bf16x8 __attribute__((ext_vector_type(8)));
typedef __bf16 bf16x4 __attribute__((ext_vector_type(4)));
typedef float  f32x4  __attribute__((ext_vector_type(4)));

#define AS1 __attribute__((address_space(1)))
#define AS3 __attribute__((address_space(3)))
__device__ __forceinline__ void glds16(const void* g, void* l) {
    __builtin_amdgcn_global_load_lds((const AS1 void*)g, (AS3 void*)l, 16, 0, 0);
}

// ---------------- fused prep: GN-stats (0..255) + weight transpose (256..575)
// + combined bias bc (576..607, 32-block parallel) + bf16 copy of attn_w (608..671)
__global__ __launch_bounds__(256) void gnw_kernel(const float* __restrict__ x,
        float* __restrict__ mu, float* __restrict__ rstd,
        const float* __restrict__ w0, const float* __restrict__ w1,
        const float* __restrict__ w2, const float* __restrict__ w3,
        const float* __restrict__ w4, bf16* __restrict__ wT,
        const float* __restrict__ attnb, const float* __restrict__ outb,
        float* __restrict__ bcv) {
    __shared__ float smem[64*65];
    int tid = threadIdx.x;
    if (blockIdx.x < 256) {
        float* s_sum = smem;
        float* s_sq  = smem + 256;
        int bg = blockIdx.x;
        long base = (long)bg * 8192;
        float sum = 0.f, sq = 0.f;
#pragma unroll
        for (int r = 0; r < 32; ++r) {
            float v = x[base + r*256 + tid];
            sum += v; sq += v*v;
        }
        s_sum[tid] = sum; s_sq[tid] = sq;
        __syncthreads();
        for (int off = 128; off > 0; off >>= 1) {
            if (tid < off) { s_sum[tid] += s_sum[tid+off]; s_sq[tid] += s_sq[tid+off]; }
            __syncthreads();
        }
        if (tid == 0) {
            float m = s_sum[0] * (1.f/8192.f);
            float v = s_sq[0]  * (1.f/8192.f) - m*m;
            mu[bg] = m;
            rstd[bg] = rsqrtf(v + 1e-5f);
        }
    } else if (blockIdx.x < 576) {
        int bid = blockIdx.x - 256;
        int z = bid >> 6, r2 = bid & 63;
        int k0 = (r2 >> 3)*64, n0 = (r2 & 7)*64;
        const float* srcs[5] = {w0, w1, w2, w3, w4};
        const float* W = srcs[z];
        bf16* D = wT + (long)z * (CCH*CCH);
        float (*t)[65] = (float(*)[65])smem;
        int cI = tid & 63, r4 = tid >> 6;
#pragma unroll
        for (int p = 0; p < 16; ++p) {
            int kr = p*4 + r4;
            t[kr][cI] = W[(long)(k0+kr)*CCH + n0 + cI];
        }
        __syncthreads();
#pragma unroll
        for (int p = 0; p < 16; ++p) {
            int nr = p*4 + r4;
            D[(long)(n0+nr)*CCH + k0 + cI] = (bf16)t[cI][nr];
        }
    } else if (blockIdx.x < 608) {
        // bc[n] = out_b[n] + sum_j attn_b[j]*w4[j][n]; 32 blocks x 16 n-cols,
        // j split across 256 threads (2 each), LDS tree-reduce.
        int n0 = (blockIdx.x - 576) * 16;
        float part[16];
#pragma unroll
        for (int i = 0; i < 16; ++i) part[i] = 0.f;
#pragma unroll
        for (int jj = 0; jj < 2; ++jj) {
            int j = tid*2 + jj;
            float a = attnb[j];
            const float* wr = w4 + (long)j*CCH + n0;
#pragma unroll
            for (int p = 0; p < 4; ++p) {
                float4 v4 = *(const float4*)(wr + p*4);
                part[p*4+0] += a*v4.x; part[p*4+1] += a*v4.y;
                part[p*4+2] += a*v4.z; part[p*4+3] += a*v4.w;
            }
        }
        float (*red)[16] = (float(*)[16])smem;   // 16 KB
#pragma unroll
        for (int i = 0; i < 16; ++i) red[tid][i] = part[i];
        __syncthreads();
        for (int off = 128; off > 0; off >>= 1) {
            if (tid < off)
#pragma unroll
                for (int i = 0; i < 16; ++i) red[tid][i] += red[tid+off][i];
            __syncthreads();
        }
        if (tid < 16) bcv[n0 + tid] = red[0][tid] + outb[n0 + tid];
    } else {
        // straight bf16 copy of attn_w into wT slot 5
        bf16* wAc = wT + (long)5*CCH*CCH;
        int base = (blockIdx.x - 608)*4096 + tid;
#pragma unroll
        for (int p = 0; p < 16; ++p)
            wAc[base + p*256] = (bf16)w3[base + p*256];
    }
}

// ---------------- transpose+norm: x (B,C,S) fp32 -> xnT (B,S,C) bf16
__global__ void tn_kernel(const float* __restrict__ x, const float* __restrict__ mu,
                          const float* __restrict__ rstd, const float* __restrict__ gsc,
                          const float* __restrict__ gbs, bf16* __restrict__ xnT) {
    __shared__ float t[64][65];
    int s0 = blockIdx.x*64, c0 = blockIdx.y*64, b = blockIdx.z;
    int tid = threadIdx.x;
    int cI = tid & 63, r4 = tid >> 6;
#pragma unroll
    for (int p = 0; p < 16; ++p) {
        int cr = p*4 + r4;
        t[cr][cI] = x[((long)(b*CCH + c0 + cr))*SSQ + s0 + cI];
    }
    __syncthreads();
#pragma unroll
    for (int p = 0; p < 16; ++p) {
        int sr = p*4 + r4;
        int c = c0 + cI;
        int g = b*128 + (c >> 2);
        float v = (t[cI][sr] - mu[g]) * rstd[g] * gsc[c] + gbs[c];
        xnT[((long)(b*SSQ + s0 + sr))*CCH + c] = (bf16)v;
    }
}

// ---------------- fused depthwise 3x3 (SAME) q/k/v on (B,S,C) bf16
// Weight loads vectorized: float4 pairs (216 -> 54 VMEM instrs/thread)
__global__ __launch_bounds__(256) void dw3_kernel(const bf16* __restrict__ xnT,
        const float* __restrict__ dwq, const float* __restrict__ dwk,
        const float* __restrict__ dwv,
        bf16* __restrict__ yq, bf16* __restrict__ yk, bf16* __restrict__ yv) {
    int tid = threadIdx.x;
    int cc = (tid & 63) * 8;
    int s  = blockIdx.x*4 + (tid >> 6);
    int sl = s & (SSQ-1);
    int b  = s >> 11;
    int m = sl >> 7, t = sl & 127;
    float aq[8] = {}, ak[8] = {}, av[8] = {};
#pragma unroll
    for (int di = 0; di < 3; ++di) {
        int m2 = m + di - 1;
        if ((unsigned)m2 >= 16u) continue;
#pragma unroll
        for (int dj = 0; dj < 3; ++dj) {
            int t2 = t + dj - 1;
            if ((unsigned)t2 >= 128u) continue;
            bf16x8 xv = *(const bf16x8*)(xnT + ((long)(b*SSQ + m2*128 + t2))*CCH + cc);
            int wi = (di*3 + dj)*CCH + cc;
            float wq[8], wk[8], wv[8];
            *(float4*)&wq[0] = *(const float4*)(dwq + wi);
            *(float4*)&wq[4] = *(const float4*)(dwq + wi + 4);
            *(float4*)&wk[0] = *(const float4*)(dwk + wi);
            *(float4*)&wk[4] = *(const float4*)(dwk + wi + 4);
            *(float4*)&wv[0] = *(const float4*)(dwv + wi);
            *(float4*)&wv[4] = *(const float4*)(dwv + wi + 4);
#pragma unroll
            for (int i = 0; i < 8; ++i) {
                float xf = (float)xv[i];
                aq[i] += xf * wq[i];
                ak[i] += xf * wk[i];
                av[i] += xf * wv[i];
            }
        }
    }
    bf16x8 oq, ok, ov;
#pragma unroll
    for (int i = 0; i < 8; ++i) { oq[i] = (bf16)aq[i]; ok[i] = (bf16)ak[i]; ov[i] = (bf16)av[i]; }
    long o = (long)s*CCH + cc;
    *(bf16x8*)(yq + o) = oq;
    *(bf16x8*)(yk + o) = ok;
    *(bf16x8*)(yv + o) = ov;
}

// ---------------- GEMM core, m97 structure: BM=128, BN=NFR*32, BK=64.
template<int NFR>
__device__ __forceinline__ void gemm_core128(const bf16* __restrict__ A,
        const bf16* __restrict__ Wt, int m0, int n0,
        bf16* As, bf16* Bs, f32x4 (&acc)[4][NFR]) {
    int tid = threadIdx.x, lane = tid & 63, wid = tid >> 6;
    int sw = wid & 1, nw = wid >> 1;
    int col = lane & 15, quad = lane >> 4;
    const char* gA[4]; char* ldsA[4];
#pragma unroll
    for (int p = 0; p < 4; ++p) {
        int ci = tid + p*256;              // 1024 chunks of 16B (128 rows x 8)
        int row = ci >> 3;
        int c = (ci & 7) ^ (row & 7);
        gA[p] = (const char*)A + ((long)(m0+row)*CCH + c*8)*2;
        ldsA[p] = (char*)As + ci*16;
    }
    const char* gB[NFR]; char* ldsB[NFR];
#pragma unroll
    for (int p = 0; p < NFR; ++p) {
        int ci = tid + p*256;              // NFR*256 chunks (BN rows x 8)
        int row = ci >> 3;
        int c = (ci & 7) ^ (row & 7);
        gB[p] = (const char*)Wt + ((long)(n0+row)*CCH + c*8)*2;
        ldsB[p] = (char*)Bs + ci*16;
    }
    int rowA = sw*64 + col;
    int rowB = nw*(NFR*16) + col;
    for (int k0 = 0; k0 < CCH; k0 += 64) {
        __syncthreads();
#pragma unroll
        for (int p = 0; p < 4; ++p)   glds16(gA[p] + k0*2, ldsA[p]);
#pragma unroll
        for (int p = 0; p < NFR; ++p) glds16(gB[p] + k0*2, ldsB[p]);
        __syncthreads();
        bf16x8 af[4][2], bfr[NFR][2];
#pragma unroll
        for (int mt = 0; mt < 4; ++mt) {
            int r = rowA + mt*16;
#pragma unroll
            for (int ks = 0; ks < 2; ++ks) {
                int c = (ks*4 + quad) ^ (r & 7);
                af[mt][ks] = *(const bf16x8*)((char*)As + r*128 + c*16);
            }
        }
#pragma unroll
        for (int nt = 0; nt < NFR; ++nt) {
            int r = rowB + nt*16;
#pragma unroll
            for (int ks = 0; ks < 2; ++ks) {
                int c = (ks*4 + quad) ^ (r & 7);
                bfr[nt][ks] = *(const bf16x8*)((char*)Bs + r*128 + c*16);
            }
        }
#pragma unroll
        for (int ks = 0; ks < 2; ++ks)
#pragma unroll
            for (int mt = 0; mt < 4; ++mt)
#pragma unroll
                for (int nt = 0; nt < NFR; ++nt)
                    acc[mt][nt] = __builtin_amdgcn_mfma_f32_16x16x32_bf16(
                        af[mt][ks], bfr[nt][ks], acc[mt][nt], 0,0,0);
    }
}

// ---------------- fused QKV GEMM, 128x128 tiles (NFR=4)
// z=0: rope*0.125 -> qout; z=1: rope -> kout
// z=2: transpose -> vout (B,C,S) with key order PERMUTED within each 32-key
//      block (pos = quad*8 + sub16*4 + r) so attn's PV B-frag is one b128
// z=3 (blocks x<4): WcT = (Wa@Wo)^T from wTo,wAc -> wT slot 6
__global__ __launch_bounds__(256) void gemm_qkv(const bf16* __restrict__ Abase,
        bf16* __restrict__ wT, bf16* __restrict__ qout,
        bf16* __restrict__ kout, bf16* __restrict__ vout) {
    __shared__ bf16 As[128*64];
    __shared__ bf16 Bs[128*64];
    int z = blockIdx.z;
    if (z == 3 && blockIdx.x >= 4) return;
    int m0 = blockIdx.x*128, n0 = blockIdx.y*128;
    const bf16* Aop = (z < 3) ? Abase + (long)z*MTOT*CCH : wT + (long)4*CCH*CCH;
    const bf16* Wop = (z < 3) ? wT + (long)z*CCH*CCH   : wT + (long)5*CCH*CCH;
    f32x4 acc[4][4] = {};
    gemm_core128<4>(Aop, Wop, m0, n0, As, Bs, acc);
    int tid = threadIdx.x, lane = tid & 63, wid = tid >> 6;
    int sw = wid & 1, nw = wid >> 1;
    int col = lane & 15, quad = lane >> 4;
    int nbase = n0 + nw*64;            // one full head (64 ch), head-aligned
    int mb = m0 + sw*64;
    if (z == 3) {
        bf16* wCt = wT + (long)6*CCH*CCH;
#pragma unroll
        for (int nt = 0; nt < 4; ++nt) {
            int n = nbase + nt*16 + col;
#pragma unroll
            for (int mt = 0; mt < 4; ++mt)
#pragma unroll
                for (int r = 0; r < 4; ++r)
                    wCt[(long)(mb + mt*16 + quad*4 + r)*CCH + n] = (bf16)acc[mt][nt][r];
        }
    } else if (z < 2) {
        bf16* outp = z ? kout : qout;
        const float sc = z ? 1.0f : 0.125f;
        float invf = __expf(-(float)col * 0.5756462732485114f);  // 10000^(-col/16)
#pragma unroll
        for (int mt = 0; mt < 4; ++mt)
#pragma unroll
            for (int r = 0; r < 4; ++r) {
                int row = mb + mt*16 + quad*4 + r;
                int sl = row & (SSQ-1);
#pragma unroll
                for (int half = 0; half < 2; ++half) {   // 0: f-rot (pos=m), 1: t-rot (pos=t)
                    float pos = half ? (float)(sl & 127) : (float)(sl >> 7);
                    float ang = pos * invf;
                    float sn, cs;
                    __sincosf(ang, &sn, &cs);
                    float x1 = acc[mt][half*2+0][r], x2 = acc[mt][half*2+1][r];
                    outp[(long)row*CCH + nbase + half*32 + col]      = (bf16)((x1*cs - x2*sn)*sc);
                    outp[(long)row*CCH + nbase + half*32 + 16 + col] = (bf16)((x1*sn + x2*cs)*sc);
                }
            }
    } else {
#pragma unroll
        for (int mt = 0; mt < 4; ++mt)
#pragma unroll
            for (int nt = 0; nt < 4; ++nt) {
                int n = nbase + nt*16 + col;
                int row0 = mb + mt*16 + quad*4;
                int bq = row0 >> 11, sl0 = row0 & (SSQ-1);
                int sub16 = (sl0 >> 4) & 1;
                long slp = (long)(sl0 & ~31) + quad*8 + sub16*4;
                bf16x4 pk;
#pragma unroll
                for (int r = 0; r < 4; ++r) pk[r] = (bf16)acc[mt][nt][r];
                *(bf16x4*)(vout + ((long)(bq*CCH + n))*SSQ + slp) = pk;
            }
    }
}

// ---------------- projection GEMM (128x64): +bias+resid -> fp32 (B,C,S) [d_out]
__global__ __launch_bounds__(256) void gemm_out(const bf16* __restrict__ A,
        const bf16* __restrict__ Wt, const float* __restrict__ bias,
        const float* __restrict__ resid, float* __restrict__ outp) {
    __shared__ bf16 As[128*64];
    __shared__ bf16 Bs[64*64];
    int m0 = blockIdx.x*128, n0 = blockIdx.y*64;
    f32x4 acc[4][2] = {};
    gemm_core128<2>(A, Wt, m0, n0, As, Bs, acc);
    int tid = threadIdx.x, lane = tid & 63, wid = tid >> 6;
    int sw = wid & 1, nw = wid >> 1;
    int col = lane & 15, quad = lane >> 4;
    int nb = n0 + nw*32, mb = m0 + sw*64;
#pragma unroll
    for (int mt = 0; mt < 4; ++mt)
#pragma unroll
        for (int nt = 0; nt < 2; ++nt) {
            int n = nb + nt*16 + col;
            float bv = bias[n];
            int row0 = mb + mt*16 + quad*4;
            int b = row0 >> 11, sl0 = row0 & (SSQ-1);
            long off = ((long)(b*CCH + n))*SSQ + sl0;
            float4 rr = *(const float4*)(resid + off);
            float4 o4;
            o4.x = acc[mt][nt][0] + bv + rr.x;
            o4.y = acc[mt][nt][1] + bv + rr.y;
            o4.z = acc[mt][nt][2] + bv + rr.z;
            o4.w = acc[mt][nt][3] + bv + rr.w;
            *(float4*)(outp + off) = o4;
        }
}

// ---------------- MFMA flash attention v11 (R7/R9-verified)
__global__ __launch_bounds__(256, 2) void attn_kernel(
        const bf16* __restrict__ qb, const bf16* __restrict__ kb,
        const bf16* __restrict__ vb, const int* __restrict__ lengths,
        bf16* __restrict__ o) {
    __shared__ char KVs[2][32768];       // [buf][ K: wid*4K | 16K + V: wid*4K ]
    __shared__ float Lsm[4][4][16];      // [wave][qt][col]
    int bid = blockIdx.x;
    int bh = bid & 15, qtb = bid >> 4;   // bh low bits -> XCD locality for K/V
    int b = bh >> 3, h = bh & 7;
    int tid = threadIdx.x, wid = tid >> 6, lane = tid & 63;
    int col = lane & 15, quad = lane >> 4;
    int q0 = qtb*64;
    int lenb = lengths[b];
    int thr = lenb - wid*32 - quad*4;    // key sub*16+r valid iff sub*16+r < thr

    const char* gK[4]; const char* gV[4];
#pragma unroll
    for (int j = 0; j < 4; ++j) {
        int s = j*64 + lane;
        int rl = s >> 3;
        int cin = s & 7;
        int csrc = cin ^ (rl & 7);
        gK[j] = (const char*)kb + ((long)(b*SSQ + wid*32 + rl))*1024 + h*128 + csrc*16;
        gV[j] = (const char*)vb + ((long)(b*CCH + h*64 + j*16 + col))*4096 + (wid*4 + quad)*16;
    }
    char* ldsK = (char*)KVs + wid*4096 + lane*16;
    char* ldsV = (char*)KVs + 16384 + wid*4096 + lane*16;

    const bf16* qp = qb + (long)(b*SSQ)*CCH + h*64;
    bf16x8 qf[4][2];
#pragma unroll
    for (int qt = 0; qt < 4; ++qt)
#pragma unroll
        for (int dc = 0; dc < 2; ++dc)
            qf[qt][dc] = *(const bf16x8*)(qp + (long)(q0 + qt*16 + col)*CCH + dc*32 + quad*8);

    f32x4 of[4][4] = {};
    float ls[4] = {};
    int cswz7 = col & 7;
    int kc0 = (quad ^ cswz7)*16;              // dc=0 chunk
    int kc1 = ((4 + quad) ^ cswz7)*16;        // dc=1 chunk

    // prologue: stage tiles 0 and 1 (16 outstanding; never drained to 0 in-loop)
#pragma unroll
    for (int j = 0; j < 4; ++j) glds16(gK[j], ldsK + j*1024);
#pragma unroll
    for (int j = 0; j < 4; ++j) glds16(gV[j], ldsV + j*1024);
#pragma unroll
    for (int j = 0; j < 4; ++j) glds16(gK[j] + 131072L, ldsK + 32768 + j*1024);
#pragma unroll
    for (int j = 0; j < 4; ++j) glds16(gV[j] + 256L, ldsV + 32768 + j*1024);

    for (int t = 0; t < 16; ++t) {
        if (t == 15) { asm volatile("s_waitcnt vmcnt(0)" ::: "memory"); }
        else         { asm volatile("s_waitcnt vmcnt(8)" ::: "memory"); }
        __builtin_amdgcn_sched_barrier(0);
        const char* K = KVs[t & 1] + wid*4096;
        const char* V = KVs[t & 1] + 16384 + wid*4096;
        bf16x8 kf[2][2], vf[4];
#pragma unroll
        for (int sub = 0; sub < 2; ++sub) {
            kf[sub][0] = *(const bf16x8*)(K + sub*2048 + col*128 + kc0);
            kf[sub][1] = *(const bf16x8*)(K + sub*2048 + col*128 + kc1);
        }
#pragma unroll
        for (int dt = 0; dt < 4; ++dt)
            vf[dt] = *(const bf16x8*)(V + dt*1024 + lane*16);
        asm volatile("s_waitcnt lgkmcnt(0)" ::: "memory");
        __builtin_amdgcn_sched_barrier(0);
        if (t < 14) {
            int bsel = (t & 1)*32768;
#pragma unroll
            for (int j = 0; j < 4; ++j) glds16(gK[j] + (long)(t+2)*131072, ldsK + bsel + j*1024);
#pragma unroll
            for (int j = 0; j < 4; ++j) glds16(gV[j] + (long)(t+2)*256,    ldsV + bsel + j*1024);
        }
        __builtin_amdgcn_sched_barrier(0);
        f32x4 sc[2][4];
#pragma unroll
        for (int sub = 0; sub < 2; ++sub) {
            f32x4 m;
#pragma unroll
            for (int r = 0; r < 4; ++r) m[r] = (sub*16 + r < thr) ? 0.f : -10000.f;
#pragma unroll
            for (int qt = 0; qt < 4; ++qt) sc[sub][qt] = m;
        }
        __builtin_amdgcn_s_setprio(1);
#pragma unroll
        for (int sub = 0; sub < 2; ++sub)
#pragma unroll
            for (int qt = 0; qt < 4; ++qt) {
                sc[sub][qt] = __builtin_amdgcn_mfma_f32_16x16x32_bf16(kf[sub][0], qf[qt][0], sc[sub][qt], 0,0,0);
                sc[sub][qt] = __builtin_amdgcn_mfma_f32_16x16x32_bf16(kf[sub][1], qf[qt][1], sc[sub][qt], 0,0,0);
            }
        __builtin_amdgcn_s_setprio(0);
        bf16x8 pf[4];
#pragma unroll
        for (int qt = 0; qt < 4; ++qt) {
            float s = 0.f;
#pragma unroll
            for (int r = 0; r < 4; ++r) {
                float e0 = __expf(sc[0][qt][r]);
                float e1 = __expf(sc[1][qt][r]);
                pf[qt][r]     = (bf16)e0;
                pf[qt][4 + r] = (bf16)e1;
                s += e0 + e1;
            }
            ls[qt] += s;
        }
        __builtin_amdgcn_s_setprio(1);
#pragma unroll
        for (int dt = 0; dt < 4; ++dt)
#pragma unroll
            for (int qt = 0; qt < 4; ++qt)
                of[qt][dt] = __builtin_amdgcn_mfma_f32_16x16x32_bf16(pf[qt], vf[dt], of[qt][dt], 0,0,0);
        __builtin_amdgcn_s_setprio(0);
    }

#pragma unroll
    for (int qt = 0; qt < 4; ++qt) {
        ls[qt] += __shfl_xor(ls[qt], 16);
        ls[qt] += __shfl_xor(ls[qt], 32);
    }
    __syncthreads();
    float* Om = (float*)KVs;             // [wave][64 rows][64 d]
#pragma unroll
    for (int qt = 0; qt < 4; ++qt)
#pragma unroll
        for (int dt = 0; dt < 4; ++dt)
#pragma unroll
            for (int r = 0; r < 4; ++r)
                Om[(wid*64 + qt*16 + quad*4 + r)*64 + dt*16 + col] = of[qt][dt][r];
    if (quad == 0)
#pragma unroll
        for (int qt = 0; qt < 4; ++qt) Lsm[wid][qt][col] = ls[qt];
    __syncthreads();
    bf16* ob = o + (long)(b*SSQ + q0)*CCH + h*64;
#pragma unroll
    for (int i = 0; i < 16; ++i) {
        int rr = wid*16 + i;
        float v = Om[rr*64 + lane] + Om[(64 + rr)*64 + lane]
                + Om[(128 + rr)*64 + lane] + Om[(192 + rr)*64 + lane];
        float l = Lsm[0][wid][i] + Lsm[1][wid][i] + Lsm[2][wid][i] + Lsm[3][wid][i];
        ob[(long)rr*CCH + lane] = (bf16)(v / l);
    }
}

extern "C" void kernel_launch(void* const* d_in, const int* in_sizes, int n_in,
                              void* d_out, int out_size, void* d_ws, size_t ws_size,
                              hipStream_t stream) {
    const float* x        = (const float*)d_in[0];
    const int*   lengths  = (const int*)  d_in[1];
    const float* gn_scale = (const float*)d_in[2];
    const float* gn_bias  = (const float*)d_in[3];
    const float* dw_q     = (const float*)d_in[4];
    const float* dw_k     = (const float*)d_in[5];
    const float* dw_v     = (const float*)d_in[6];
    const float* pw_q     = (const float*)d_in[7];
    const float* pw_k     = (const float*)d_in[8];
    const float* pw_v     = (const float*)d_in[9];
    const float* attn_w   = (const float*)d_in[10];
    const float* attn_b   = (const float*)d_in[11];
    const float* out_w    = (const float*)d_in[12];
    const float* out_b    = (const float*)d_in[13];
    float* out = (float*)d_out;

    char* w = (char*)d_ws;
    float* mu   = (float*)w;
    float* rstd = (float*)(w + 1024);
    float* bcv  = (float*)(w + 2048);
    bf16* wT    = (bf16*)(w + 4096);          // 7 slots x 512KB:
                                              // 0..2 pw_{q,k,v}^T, 3 Wa^T, 4 Wo^T, 5 Wa, 6 Wc^T
    bf16* wCt = wT + (long)6*CCH*CCH;
    bf16* xnT  = (bf16*)(w + 0x00400000);
    bf16* yT   = (bf16*)(w + 0x00800000);     // yq|yk|yv contiguous, 4MB each
    bf16* qbf  = (bf16*)(w + 0x01400000);
    bf16* kbf  = (bf16*)(w + 0x01800000);
    bf16* vbf  = (bf16*)(w + 0x01C00000);
    bf16* obf  = (bf16*)(w + 0x02000000);

    gnw_kernel<<<672, 256, 0, stream>>>(x, mu, rstd, pw_q, pw_k, pw_v, attn_w, out_w,
                                        wT, attn_b, out_b, bcv);
    tn_kernel<<<dim3(32,8,2), 256, 0, stream>>>(x, mu, rstd, gn_scale, gn_bias, xnT);
    dw3_kernel<<<MTOT/4, 256, 0, stream>>>(xnT, dw_q, dw_k, dw_v,
                                           yT, yT + (long)MTOT*CCH, yT + (long)2*MTOT*CCH);

    gemm_qkv<<<dim3(MTOT/128, CCH/128, 4), 256, 0, stream>>>(yT, wT, qbf, kbf, vbf);

    attn_kernel<<<512, 256, 0, stream>>>(qbf, kbf, vbf, lengths, obf);

    gemm_out<<<dim3(MTOT/128, CCH/64), 256, 0, stream>>>(obf, wCt, bcv, x, out);
}

// Round 12
// 154.616 us; speedup vs baseline: 1.0610x; 1.0031x over previous
//
#include <hip/hip_runtime.h>
#include <math.h>

#define CCH 512
#define SSQ 2048           // M*T
#define MTOT 4096          // B*S rows

typedef __bf16 bf16;
typedef __bf16 bf16x8 __attribute__((ext_vector_type(8)));
typedef __bf16 bf16x4 __attribute__((ext_vector_type(4)));
typedef float  f32x4  __attribute__((ext_vector_type(4)));

#define AS1 __attribute__((address_space(1)))
#define AS3 __attribute__((address_space(3)))
__device__ __forceinline__ void glds16(const void* g, void* l) {
    __builtin_amdgcn_global_load_lds((const AS1 void*)g, (AS3 void*)l, 16, 0, 0);
}
// raw v_exp_f32: computes 2^x (masked lanes: 2^-10000 flushes to 0)
__device__ __forceinline__ float fexp2(float x) {
    float r; asm("v_exp_f32 %0, %1" : "=v"(r) : "v"(x)); return r;
}

// ---------------- fused prep: GN-stats (0..255) + weight transpose (256..575)
// + combined bias bc (576..607) + bf16 copy of attn_w (608..671)
// + rope cos/sin table (672..680): t0[16][16] (pos=m), t1[128][16] (pos=t)
__global__ __launch_bounds__(256) void gnw_kernel(const float* __restrict__ x,
        float* __restrict__ mu, float* __restrict__ rstd,
        const float* __restrict__ w0, const float* __restrict__ w1,
        const float* __restrict__ w2, const float* __restrict__ w3,
        const float* __restrict__ w4, bf16* __restrict__ wT,
        const float* __restrict__ attnb, const float* __restrict__ outb,
        float* __restrict__ bcv, float2* __restrict__ rtab) {
    __shared__ float smem[64*65];
    int tid = threadIdx.x;
    if (blockIdx.x < 256) {
        float* s_sum = smem;
        float* s_sq  = smem + 256;
        int bg = blockIdx.x;
        long base = (long)bg * 8192;
        float sum = 0.f, sq = 0.f;
#pragma unroll
        for (int r = 0; r < 32; ++r) {
            float v = x[base + r*256 + tid];
            sum += v; sq += v*v;
        }
        s_sum[tid] = sum; s_sq[tid] = sq;
        __syncthreads();
        for (int off = 128; off > 0; off >>= 1) {
            if (tid < off) { s_sum[tid] += s_sum[tid+off]; s_sq[tid] += s_sq[tid+off]; }
            __syncthreads();
        }
        if (tid == 0) {
            float m = s_sum[0] * (1.f/8192.f);
            float v = s_sq[0]  * (1.f/8192.f) - m*m;
            mu[bg] = m;
            rstd[bg] = rsqrtf(v + 1e-5f);
        }
    } else if (blockIdx.x < 576) {
        int bid = blockIdx.x - 256;
        int z = bid >> 6, r2 = bid & 63;
        int k0 = (r2 >> 3)*64, n0 = (r2 & 7)*64;
        const float* srcs[5] = {w0, w1, w2, w3, w4};
        const float* W = srcs[z];
        bf16* D = wT + (long)z * (CCH*CCH);
        float (*t)[65] = (float(*)[65])smem;
        int cI = tid & 63, r4 = tid >> 6;
#pragma unroll
        for (int p = 0; p < 16; ++p) {
            int kr = p*4 + r4;
            t[kr][cI] = W[(long)(k0+kr)*CCH + n0 + cI];
        }
        __syncthreads();
#pragma unroll
        for (int p = 0; p < 16; ++p) {
            int nr = p*4 + r4;
            D[(long)(n0+nr)*CCH + k0 + cI] = (bf16)t[cI][nr];
        }
    } else if (blockIdx.x < 608) {
        // bc[n] = out_b[n] + sum_j attn_b[j]*w4[j][n]; 32 blocks x 16 n-cols
        int n0 = (blockIdx.x - 576) * 16;
        float part[16];
#pragma unroll
        for (int i = 0; i < 16; ++i) part[i] = 0.f;
#pragma unroll
        for (int jj = 0; jj < 2; ++jj) {
            int j = tid*2 + jj;
            float a = attnb[j];
            const float* wr = w4 + (long)j*CCH + n0;
#pragma unroll
            for (int p = 0; p < 4; ++p) {
                float4 v4 = *(const float4*)(wr + p*4);
                part[p*4+0] += a*v4.x; part[p*4+1] += a*v4.y;
                part[p*4+2] += a*v4.z; part[p*4+3] += a*v4.w;
            }
        }
        float (*red)[16] = (float(*)[16])smem;   // 16 KB
#pragma unroll
        for (int i = 0; i < 16; ++i) red[tid][i] = part[i];
        __syncthreads();
        for (int off = 128; off > 0; off >>= 1) {
            if (tid < off)
#pragma unroll
                for (int i = 0; i < 16; ++i) red[tid][i] += red[tid+off][i];
            __syncthreads();
        }
        if (tid < 16) bcv[n0 + tid] = red[0][tid] + outb[n0 + tid];
    } else if (blockIdx.x < 672) {
        // straight bf16 copy of attn_w into wT slot 5
        bf16* wAc = wT + (long)5*CCH*CCH;
        int base = (blockIdx.x - 608)*4096 + tid;
#pragma unroll
        for (int p = 0; p < 16; ++p)
            wAc[base + p*256] = (bf16)w3[base + p*256];
    } else {
        // rope table: idx<256 -> t0[pos(0..15)][col], else t1[pos(0..127)][col]
        int idx = (blockIdx.x - 672)*256 + tid;    // 0..2303
        if (idx < 2304) {
            int j = (idx < 256) ? idx : idx - 256;
            int pos = j >> 4, c = j & 15;
            float invf = __expf(-(float)c * 0.5756462732485114f);  // 10000^(-c/16)
            float sn, cs;
            __sincosf((float)pos * invf, &sn, &cs);
            rtab[idx].x = cs;
            rtab[idx].y = sn;
        }
    }
}

// ---------------- transpose+norm: x (B,C,S) fp32 -> xnT (B,S,C) bf16
__global__ void tn_kernel(const float* __restrict__ x, const float* __restrict__ mu,
                          const float* __restrict__ rstd, const float* __restrict__ gsc,
                          const float* __restrict__ gbs, bf16* __restrict__ xnT) {
    __shared__ float t[64][65];
    int s0 = blockIdx.x*64, c0 = blockIdx.y*64, b = blockIdx.z;
    int tid = threadIdx.x;
    int cI = tid & 63, r4 = tid >> 6;
#pragma unroll
    for (int p = 0; p < 16; ++p) {
        int cr = p*4 + r4;
        t[cr][cI] = x[((long)(b*CCH + c0 + cr))*SSQ + s0 + cI];
    }
    __syncthreads();
#pragma unroll
    for (int p = 0; p < 16; ++p) {
        int sr = p*4 + r4;
        int c = c0 + cI;
        int g = b*128 + (c >> 2);
        float v = (t[cI][sr] - mu[g]) * rstd[g] * gsc[c] + gbs[c];
        xnT[((long)(b*SSQ + s0 + sr))*CCH + c] = (bf16)v;
    }
}

// ---------------- fused depthwise 3x3 (SAME) q/k/v on (B,S,C) bf16
// Weight loads vectorized: float4 pairs
__global__ __launch_bounds__(256) void dw3_kernel(const bf16* __restrict__ xnT,
        const float* __restrict__ dwq, const float* __restrict__ dwk,
        const float* __restrict__ dwv,
        bf16* __restrict__ yq, bf16* __restrict__ yk, bf16* __restrict__ yv) {
    int tid = threadIdx.x;
    int cc = (tid & 63) * 8;
    int s  = blockIdx.x*4 + (tid >> 6);
    int sl = s & (SSQ-1);
    int b  = s >> 11;
    int m = sl >> 7, t = sl & 127;
    float aq[8] = {}, ak[8] = {}, av[8] = {};
#pragma unroll
    for (int di = 0; di < 3; ++di) {
        int m2 = m + di - 1;
        if ((unsigned)m2 >= 16u) continue;
#pragma unroll
        for (int dj = 0; dj < 3; ++dj) {
            int t2 = t + dj - 1;
            if ((unsigned)t2 >= 128u) continue;
            bf16x8 xv = *(const bf16x8*)(xnT + ((long)(b*SSQ + m2*128 + t2))*CCH + cc);
            int wi = (di*3 + dj)*CCH + cc;
            float wq[8], wk[8], wv[8];
            *(float4*)&wq[0] = *(const float4*)(dwq + wi);
            *(float4*)&wq[4] = *(const float4*)(dwq + wi + 4);
            *(float4*)&wk[0] = *(const float4*)(dwk + wi);
            *(float4*)&wk[4] = *(const float4*)(dwk + wi + 4);
            *(float4*)&wv[0] = *(const float4*)(dwv + wi);
            *(float4*)&wv[4] = *(const float4*)(dwv + wi + 4);
#pragma unroll
            for (int i = 0; i < 8; ++i) {
                float xf = (float)xv[i];
                aq[i] += xf * wq[i];
                ak[i] += xf * wk[i];
                av[i] += xf * wv[i];
            }
        }
    }
    bf16x8 oq, ok, ov;
#pragma unroll
    for (int i = 0; i < 8; ++i) { oq[i] = (bf16)aq[i]; ok[i] = (bf16)ak[i]; ov[i] = (bf16)av[i]; }
    long o = (long)s*CCH + cc;
    *(bf16x8*)(yq + o) = oq;
    *(bf16x8*)(yk + o) = ok;
    *(bf16x8*)(yv + o) = ov;
}

// ---------------- GEMM core, m97 structure: BM=128, BN=NFR*32, BK=64.
template<int NFR>
__device__ __forceinline__ void gemm_core128(const bf16* __restrict__ A,
        const bf16* __restrict__ Wt, int m0, int n0,
        bf16* As, bf16* Bs, f32x4 (&acc)[4][NFR]) {
    int tid = threadIdx.x, lane = tid & 63, wid = tid >> 6;
    int sw = wid & 1, nw = wid >> 1;
    int col = lane & 15, quad = lane >> 4;
    const char* gA[4]; char* ldsA[4];
#pragma unroll
    for (int p = 0; p < 4; ++p) {
        int ci = tid + p*256;              // 1024 chunks of 16B (128 rows x 8)
        int row = ci >> 3;
        int c = (ci & 7) ^ (row & 7);
        gA[p] = (const char*)A + ((long)(m0+row)*CCH + c*8)*2;
        ldsA[p] = (char*)As + ci*16;
    }
    const char* gB[NFR]; char* ldsB[NFR];
#pragma unroll
    for (int p = 0; p < NFR; ++p) {
        int ci = tid + p*256;              // NFR*256 chunks (BN rows x 8)
        int row = ci >> 3;
        int c = (ci & 7) ^ (row & 7);
        gB[p] = (const char*)Wt + ((long)(n0+row)*CCH + c*8)*2;
        ldsB[p] = (char*)Bs + ci*16;
    }
    int rowA = sw*64 + col;
    int rowB = nw*(NFR*16) + col;
    for (int k0 = 0; k0 < CCH; k0 += 64) {
        __syncthreads();
#pragma unroll
        for (int p = 0; p < 4; ++p)   glds16(gA[p] + k0*2, ldsA[p]);
#pragma unroll
        for (int p = 0; p < NFR; ++p) glds16(gB[p] + k0*2, ldsB[p]);
        __syncthreads();
        bf16x8 af[4][2], bfr[NFR][2];
#pragma unroll
        for (int mt = 0; mt < 4; ++mt) {
            int r = rowA + mt*16;
#pragma unroll
            for (int ks = 0; ks < 2; ++ks) {
                int c = (ks*4 + quad) ^ (r & 7);
                af[mt][ks] = *(const bf16x8*)((char*)As + r*128 + c*16);
            }
        }
#pragma unroll
        for (int nt = 0; nt < NFR; ++nt) {
            int r = rowB + nt*16;
#pragma unroll
            for (int ks = 0; ks < 2; ++ks) {
                int c = (ks*4 + quad) ^ (r & 7);
                bfr[nt][ks] = *(const bf16x8*)((char*)Bs + r*128 + c*16);
            }
        }
#pragma unroll
        for (int ks = 0; ks < 2; ++ks)
#pragma unroll
            for (int mt = 0; mt < 4; ++mt)
#pragma unroll
                for (int nt = 0; nt < NFR; ++nt)
                    acc[mt][nt] = __builtin_amdgcn_mfma_f32_16x16x32_bf16(
                        af[mt][ks], bfr[nt][ks], acc[mt][nt], 0,0,0);
    }
}

// ---------------- fused QKV GEMM, 128x128 tiles (NFR=4)
// z=0: rope*(0.125*log2e) -> qout (attn uses exp2); z=1: rope -> kout
// z=2: transpose -> vout (B,C,S) with key order PERMUTED within each 32-key
//      block (pos = quad*8 + sub16*4 + r) so attn's PV B-frag is one b128
// z=3 (blocks x<4): WcT = (Wa@Wo)^T from wTo,wAc -> wT slot 6
// rope angles from precomputed table rtab (t0 16x16 | t1 128x16, float2)
__global__ __launch_bounds__(256) void gemm_qkv(const bf16* __restrict__ Abase,
        bf16* __restrict__ wT, const float2* __restrict__ rtab,
        bf16* __restrict__ qout, bf16* __restrict__ kout, bf16* __restrict__ vout) {
    __shared__ bf16 As[128*64];
    __shared__ bf16 Bs[128*64];
    int z = blockIdx.z;
    if (z == 3 && blockIdx.x >= 4) return;
    int m0 = blockIdx.x*128, n0 = blockIdx.y*128;
    const bf16* Aop = (z < 3) ? Abase + (long)z*MTOT*CCH : wT + (long)4*CCH*CCH;
    const bf16* Wop = (z < 3) ? wT + (long)z*CCH*CCH   : wT + (long)5*CCH*CCH;
    f32x4 acc[4][4] = {};
    gemm_core128<4>(Aop, Wop, m0, n0, As, Bs, acc);
    int tid = threadIdx.x, lane = tid & 63, wid = tid >> 6;
    int sw = wid & 1, nw = wid >> 1;
    int col = lane & 15, quad = lane >> 4;
    int nbase = n0 + nw*64;            // one full head (64 ch), head-aligned
    int mb = m0 + sw*64;
    if (z == 3) {
        bf16* wCt = wT + (long)6*CCH*CCH;
#pragma unroll
        for (int nt = 0; nt < 4; ++nt) {
            int n = nbase + nt*16 + col;
#pragma unroll
            for (int mt = 0; mt < 4; ++mt)
#pragma unroll
                for (int r = 0; r < 4; ++r)
                    wCt[(long)(mb + mt*16 + quad*4 + r)*CCH + n] = (bf16)acc[mt][nt][r];
        }
    } else if (z < 2) {
        bf16* outp = z ? kout : qout;
        const float sc = z ? 1.0f : 0.18033688f;   // 0.125 * log2(e)
        const float2* t0 = rtab + col;             // [pos][16] stride
        const float2* t1 = rtab + 256 + col;
#pragma unroll
        for (int mt = 0; mt < 4; ++mt)
#pragma unroll
            for (int r = 0; r < 4; ++r) {
                int row = mb + mt*16 + quad*4 + r;
                int sl = row & (SSQ-1);
                float2 cf = t0[(sl >> 7) * 16];    // f-rot: pos = m
                float2 ct = t1[(sl & 127) * 16];   // t-rot: pos = t
#pragma unroll
                for (int half = 0; half < 2; ++half) {
                    float csv = half ? ct.x : cf.x;
                    float snv = half ? ct.y : cf.y;
                    float x1 = acc[mt][half*2+0][r], x2 = acc[mt][half*2+1][r];
                    outp[(long)row*CCH + nbase + half*32 + col]      = (bf16)((x1*csv - x2*snv)*sc);
                    outp[(long)row*CCH + nbase + half*32 + 16 + col] = (bf16)((x1*snv + x2*csv)*sc);
                }
            }
    } else {
#pragma unroll
        for (int mt = 0; mt < 4; ++mt)
#pragma unroll
            for (int nt = 0; nt < 4; ++nt) {
                int n = nbase + nt*16 + col;
                int row0 = mb + mt*16 + quad*4;
                int bq = row0 >> 11, sl0 = row0 & (SSQ-1);
                int sub16 = (sl0 >> 4) & 1;
                long slp = (long)(sl0 & ~31) + quad*8 + sub16*4;
                bf16x4 pk;
#pragma unroll
                for (int r = 0; r < 4; ++r) pk[r] = (bf16)acc[mt][nt][r];
                *(bf16x4*)(vout + ((long)(bq*CCH + n))*SSQ + slp) = pk;
            }
    }
}

// ---------------- projection GEMM (128x64): +bias+resid -> fp32 (B,C,S) [d_out]
__global__ __launch_bounds__(256) void gemm_out(const bf16* __restrict__ A,
        const bf16* __restrict__ Wt, const float* __restrict__ bias,
        const float* __restrict__ resid, float* __restrict__ outp) {
    __shared__ bf16 As[128*64];
    __shared__ bf16 Bs[64*64];
    int m0 = blockIdx.x*128, n0 = blockIdx.y*64;
    f32x4 acc[4][2] = {};
    gemm_core128<2>(A, Wt, m0, n0, As, Bs, acc);
    int tid = threadIdx.x, lane = tid & 63, wid = tid >> 6;
    int sw = wid & 1, nw = wid >> 1;
    int col = lane & 15, quad = lane >> 4;
    int nb = n0 + nw*32, mb = m0 + sw*64;
#pragma unroll
    for (int mt = 0; mt < 4; ++mt)
#pragma unroll
        for (int nt = 0; nt < 2; ++nt) {
            int n = nb + nt*16 + col;
            float bv = bias[n];
            int row0 = mb + mt*16 + quad*4;
            int b = row0 >> 11, sl0 = row0 & (SSQ-1);
            long off = ((long)(b*CCH + n))*SSQ + sl0;
            float4 rr = *(const float4*)(resid + off);
            float4 o4;
            o4.x = acc[mt][nt][0] + bv + rr.x;
            o4.y = acc[mt][nt][1] + bv + rr.y;
            o4.z = acc[mt][nt][2] + bv + rr.z;
            o4.w = acc[mt][nt][3] + bv + rr.w;
            *(float4*)(outp + off) = o4;
        }
}

// ---------------- MFMA flash attention v11b (R7/R9 structure + exp2 path)
__global__ __launch_bounds__(256, 2) void attn_kernel(
        const bf16* __restrict__ qb, const bf16* __restrict__ kb,
        const bf16* __restrict__ vb, const int* __restrict__ lengths,
        bf16* __restrict__ o) {
    __shared__ char KVs[2][32768];       // [buf][ K: wid*4K | 16K + V: wid*4K ]
    __shared__ float Lsm[4][4][16];      // [wave][qt][col]
    int bid = blockIdx.x;
    int bh = bid & 15, qtb = bid >> 4;   // bh low bits -> XCD locality for K/V
    int b = bh >> 3, h = bh & 7;
    int tid = threadIdx.x, wid = tid >> 6, lane = tid & 63;
    int col = lane & 15, quad = lane >> 4;
    int q0 = qtb*64;
    int lenb = lengths[b];
    int thr = lenb - wid*32 - quad*4;    // key sub*16+r valid iff sub*16+r < thr

    const char* gK[4]; const char* gV[4];
#pragma unroll
    for (int j = 0; j < 4; ++j) {
        int s = j*64 + lane;
        int rl = s >> 3;
        int cin = s & 7;
        int csrc = cin ^ (rl & 7);
        gK[j] = (const char*)kb + ((long)(b*SSQ + wid*32 + rl))*1024 + h*128 + csrc*16;
        gV[j] = (const char*)vb + ((long)(b*CCH + h*64 + j*16 + col))*4096 + (wid*4 + quad)*16;
    }
    char* ldsK = (char*)KVs + wid*4096 + lane*16;
    char* ldsV = (char*)KVs + 16384 + wid*4096 + lane*16;

    const bf16* qp = qb + (long)(b*SSQ)*CCH + h*64;
    bf16x8 qf[4][2];
#pragma unroll
    for (int qt = 0; qt < 4; ++qt)
#pragma unroll
        for (int dc = 0; dc < 2; ++dc)
            qf[qt][dc] = *(const bf16x8*)(qp + (long)(q0 + qt*16 + col)*CCH + dc*32 + quad*8);

    f32x4 of[4][4] = {};
    float ls[4] = {};
    int cswz7 = col & 7;
    int kc0 = (quad ^ cswz7)*16;              // dc=0 chunk
    int kc1 = ((4 + quad) ^ cswz7)*16;        // dc=1 chunk

    // prologue: stage tiles 0 and 1 (16 outstanding; never drained to 0 in-loop)
#pragma unroll
    for (int j = 0; j < 4; ++j) glds16(gK[j], ldsK + j*1024);
#pragma unroll
    for (int j = 0; j < 4; ++j) glds16(gV[j], ldsV + j*1024);
#pragma unroll
    for (int j = 0; j < 4; ++j) glds16(gK[j] + 131072L, ldsK + 32768 + j*1024);
#pragma unroll
    for (int j = 0; j < 4; ++j) glds16(gV[j] + 256L, ldsV + 32768 + j*1024);

    for (int t = 0; t < 16; ++t) {
        if (t == 15) { asm volatile("s_waitcnt vmcnt(0)" ::: "memory"); }
        else         { asm volatile("s_waitcnt vmcnt(8)" ::: "memory"); }
        __builtin_amdgcn_sched_barrier(0);
        const char* K = KVs[t & 1] + wid*4096;
        const char* V = KVs[t & 1] + 16384 + wid*4096;
        bf16x8 kf[2][2], vf[4];
#pragma unroll
        for (int sub = 0; sub < 2; ++sub) {
            kf[sub][0] = *(const bf16x8*)(K + sub*2048 + col*128 + kc0);
            kf[sub][1] = *(const bf16x8*)(K + sub*2048 + col*128 + kc1);
        }
#pragma unroll
        for (int dt = 0; dt < 4; ++dt)
            vf[dt] = *(const bf16x8*)(V + dt*1024 + lane*16);
        asm volatile("s_waitcnt lgkmcnt(0)" ::: "memory");
        __builtin_amdgcn_sched_barrier(0);
        if (t < 14) {
            int bsel = (t & 1)*32768;
#pragma unroll
            for (int j = 0; j < 4; ++j) glds16(gK[j] + (long)(t+2)*131072, ldsK + bsel + j*1024);
#pragma unroll
            for (int j = 0; j < 4; ++j) glds16(gV[j] + (long)(t+2)*256,    ldsV + bsel + j*1024);
        }
        __builtin_amdgcn_sched_barrier(0);
        f32x4 sc[2][4];
#pragma unroll
        for (int sub = 0; sub < 2; ++sub) {
            f32x4 m;
#pragma unroll
            for (int r = 0; r < 4; ++r) m[r] = (sub*16 + r < thr) ? 0.f : -10000.f;
#pragma unroll
            for (int qt = 0; qt < 4; ++qt) sc[sub][qt] = m;
        }
        __builtin_amdgcn_s_setprio(1);
#pragma unroll
        for (int sub = 0; sub < 2; ++sub)
#pragma unroll
            for (int qt = 0; qt < 4; ++qt) {
                sc[sub][qt] = __builtin_amdgcn_mfma_f32_16x16x32_bf16(kf[sub][0], qf[qt][0], sc[sub][qt], 0,0,0);
                sc[sub][qt] = __builtin_amdgcn_mfma_f32_16x16x32_bf16(kf[sub][1], qf[qt][1], sc[sub][qt], 0,0,0);
            }
        __builtin_amdgcn_s_setprio(0);
        bf16x8 pf[4];
#pragma unroll
        for (int qt = 0; qt < 4; ++qt) {
            float s = 0.f;
#pragma unroll
            for (int r = 0; r < 4; ++r) {
                float e0 = fexp2(sc[0][qt][r]);
                float e1 = fexp2(sc[1][qt][r]);
                pf[qt][r]     = (bf16)e0;
                pf[qt][4 + r] = (bf16)e1;
                s += e0 + e1;
            }
            ls[qt] += s;
        }
        __builtin_amdgcn_s_setprio(1);
#pragma unroll
        for (int dt = 0; dt < 4; ++dt)
#pragma unroll
            for (int qt = 0; qt < 4; ++qt)
                of[qt][dt] = __builtin_amdgcn_mfma_f32_16x16x32_bf16(pf[qt], vf[dt], of[qt][dt], 0,0,0);
        __builtin_amdgcn_s_setprio(0);
    }

#pragma unroll
    for (int qt = 0; qt < 4; ++qt) {
        ls[qt] += __shfl_xor(ls[qt], 16);
        ls[qt] += __shfl_xor(ls[qt], 32);
    }
    __syncthreads();
    float* Om = (float*)KVs;             // [wave][64 rows][64 d]
#pragma unroll
    for (int qt = 0; qt < 4; ++qt)
#pragma unroll
        for (int dt = 0; dt < 4; ++dt)
#pragma unroll
            for (int r = 0; r < 4; ++r)
                Om[(wid*64 + qt*16 + quad*4 + r)*64 + dt*16 + col] = of[qt][dt][r];
    if (quad == 0)
#pragma unroll
        for (int qt = 0; qt < 4; ++qt) Lsm[wid][qt][col] = ls[qt];
    __syncthreads();
    bf16* ob = o + (long)(b*SSQ + q0)*CCH + h*64;
#pragma unroll
    for (int i = 0; i < 16; ++i) {
        int rr = wid*16 + i;
        float v = Om[rr*64 + lane] + Om[(64 + rr)*64 + lane]
                + Om[(128 + rr)*64 + lane] + Om[(192 + rr)*64 + lane];
        float l = Lsm[0][wid][i] + Lsm[1][wid][i] + Lsm[2][wid][i] + Lsm[3][wid][i];
        ob[(long)rr*CCH + lane] = (bf16)(v / l);
    }
}

extern "C" void kernel_launch(void* const* d_in, const int* in_sizes, int n_in,
                              void* d_out, int out_size, void* d_ws, size_t ws_size,
                              hipStream_t stream) {
    const float* x        = (const float*)d_in[0];
    const int*   lengths  = (const int*)  d_in[1];
    const float* gn_scale = (const float*)d_in[2];
    const float* gn_bias  = (const float*)d_in[3];
    const float* dw_q     = (const float*)d_in[4];
    const float* dw_k     = (const float*)d_in[5];
    const float* dw_v     = (const float*)d_in[6];
    const float* pw_q     = (const float*)d_in[7];
    const float* pw_k     = (const float*)d_in[8];
    const float* pw_v     = (const float*)d_in[9];
    const float* attn_w   = (const float*)d_in[10];
    const float* attn_b   = (const float*)d_in[11];
    const float* out_w    = (const float*)d_in[12];
    const float* out_b    = (const float*)d_in[13];
    float* out = (float*)d_out;

    char* w = (char*)d_ws;
    float* mu   = (float*)w;
    float* rstd = (float*)(w + 1024);
    float* bcv  = (float*)(w + 2048);
    bf16* wT    = (bf16*)(w + 4096);          // 7 slots x 512KB (ends ~0x381000):
                                              // 0..2 pw_{q,k,v}^T, 3 Wa^T, 4 Wo^T, 5 Wa, 6 Wc^T
    bf16* wCt = wT + (long)6*CCH*CCH;
    float2* rtab = (float2*)(w + 0x00390000); // rope table: 2304 float2 (18.4KB)
    bf16* xnT  = (bf16*)(w + 0x00400000);
    bf16* yT   = (bf16*)(w + 0x00800000);     // yq|yk|yv contiguous, 4MB each
    bf16* qbf  = (bf16*)(w + 0x01400000);
    bf16* kbf  = (bf16*)(w + 0x01800000);
    bf16* vbf  = (bf16*)(w + 0x01C00000);
    bf16* obf  = (bf16*)(w + 0x02000000);

    gnw_kernel<<<681, 256, 0, stream>>>(x, mu, rstd, pw_q, pw_k, pw_v, attn_w, out_w,
                                        wT, attn_b, out_b, bcv, rtab);
    tn_kernel<<<dim3(32,8,2), 256, 0, stream>>>(x, mu, rstd, gn_scale, gn_bias, xnT);
    dw3_kernel<<<MTOT/4, 256, 0, stream>>>(xnT, dw_q, dw_k, dw_v,
                                           yT, yT + (long)MTOT*CCH, yT + (long)2*MTOT*CCH);

    gemm_qkv<<<dim3(MTOT/128, CCH/128, 4), 256, 0, stream>>>(yT, wT, rtab, qbf, kbf, vbf);

    attn_kernel<<<512, 256, 0, stream>>>(qbf, kbf, vbf, lengths, obf);

    gemm_out<<<dim3(MTOT/128, CCH/64), 256, 0, stream>>>(obf, wCt, bcv, x, out);
}